// Round 1
// baseline (1700.871 us; speedup 1.0000x reference)
//
#include <hip/hip_runtime.h>
#include <stdint.h>

#define N0 30000
#define N1 6000
#define FDIM 1024
#define HDIM 512
#define E00 600000
#define E01 300000
#define E10 300000
#define E11A 400000
#define E11B 400000
#define NE_TOT (E00 + E01 + E10 + E11A + E11B)

typedef __attribute__((ext_vector_type(4))) float f32x4;
typedef __attribute__((ext_vector_type(8))) __bf16 bf16x8;

// ---------- helpers ----------
__device__ __forceinline__ unsigned short f2bf(float f) {
  unsigned u = __float_as_uint(f);
  u += 0x7fffu + ((u >> 16) & 1u);   // round-to-nearest-even
  return (unsigned short)(u >> 16);
}

__device__ __forceinline__ void gload16(const void* g, void* l) {
  __builtin_amdgcn_global_load_lds((const __attribute__((address_space(1))) void*)g,
                                   (__attribute__((address_space(3))) void*)l, 16, 0, 0);
}

// ---------- conversion kernels ----------
__global__ void conv_bf16_kernel(const float* __restrict__ src, unsigned short* __restrict__ dst, int n4) {
  int gid = blockIdx.x * blockDim.x + threadIdx.x;
  if (gid >= n4) return;
  float4 v = ((const float4*)src)[gid];
  ushort4 o;
  o.x = f2bf(v.x); o.y = f2bf(v.y); o.z = f2bf(v.z); o.w = f2bf(v.w);
  ((ushort4*)dst)[gid] = o;
}

// Transpose-convert 5 weight matrices [K][512] f32 -> Wt blocks [N][K] bf16.
// dst0 gets (w00 | w10) stacked along N (1024 rows); dst1 gets (w01 | w11a | w11b) (1536 rows).
__global__ void conv_weights_kernel(const float* __restrict__ w00, const float* __restrict__ w10,
                                    const float* __restrict__ w01, const float* __restrict__ w11a,
                                    const float* __restrict__ w11b,
                                    unsigned short* __restrict__ dst0, unsigned short* __restrict__ dst1, int K) {
  int gid = blockIdx.x * blockDim.x + threadIdx.x;
  int total0 = 1024 * K;
  int total1 = 1536 * K;
  if (gid < total0) {
    int n = gid / K, k = gid - n * K;
    const float* w = (n < 512) ? w00 : w10;
    int nn = n & 511;
    dst0[gid] = f2bf(w[(size_t)k * 512 + nn]);
  } else if (gid < total0 + total1) {
    int g = gid - total0;
    int n = g / K, k = g - n * K;
    const float* w = (n < 512) ? w01 : ((n < 1024) ? w11a : w11b);
    int nn = n & 511;
    dst1[g] = f2bf(w[(size_t)k * 512 + nn]);
  }
}

// ---------- CSR build ----------
__global__ void zero_ints(int* p, int n) {
  int g = blockIdx.x * blockDim.x + threadIdx.x;
  if (g < n) p[g] = 0;
}

__global__ void hist5(const int* __restrict__ r0, const int* __restrict__ r1, const int* __restrict__ r2,
                      const int* __restrict__ r3, const int* __restrict__ r4,
                      int* c0, int* c1, int* c2, int* c3, int* c4) {
  int g = blockIdx.x * blockDim.x + threadIdx.x;
  const int* r; int* c; int e;
  if (g < E00) { r = r0; c = c0; e = g; }
  else if (g < E00 + E01) { r = r1; c = c1; e = g - E00; }
  else if (g < E00 + E01 + E10) { r = r2; c = c2; e = g - (E00 + E01); }
  else if (g < E00 + E01 + E10 + E11A) { r = r3; c = c3; e = g - (E00 + E01 + E10); }
  else if (g < NE_TOT) { r = r4; c = c4; e = g - (E00 + E01 + E10 + E11A); }
  else return;
  atomicAdd(&c[r[e]], 1);
}

// one wave per adjacency: exclusive scan of counts -> rowptr, counts become cursors
__global__ void scan5(int* c0, int* rp0, int* c1, int* rp1, int* c2, int* rp2,
                      int* c3, int* rp3, int* c4, int* rp4) {
  int w = threadIdx.x >> 6, lane = threadIdx.x & 63;
  int* cnt; int* rp; int n;
  if (w == 0) { cnt = c0; rp = rp0; n = N0; }
  else if (w == 1) { cnt = c1; rp = rp1; n = N0; }
  else if (w == 2) { cnt = c2; rp = rp2; n = N1; }
  else if (w == 3) { cnt = c3; rp = rp3; n = N1; }
  else { cnt = c4; rp = rp4; n = N1; }
  int carry = 0;
  for (int base = 0; base < n; base += 64) {
    int i = base + lane;
    int v = (i < n) ? cnt[i] : 0;
    int x = v;
    #pragma unroll
    for (int d = 1; d < 64; d <<= 1) {
      int y = __shfl_up(x, d, 64);
      if (lane >= d) x += y;
    }
    int total = __shfl(x, 63, 64);
    int excl = carry + x - v;
    if (i < n) { rp[i] = excl; cnt[i] = excl; }
    carry += total;
  }
  if (lane == 0) rp[n] = carry;
}

__global__ void scatter5(const int* __restrict__ r0, const int* __restrict__ q0, const float* __restrict__ v0,
                         int* cur0, int* sc0, float* sv0,
                         const int* __restrict__ r1, const int* __restrict__ q1, const float* __restrict__ v1,
                         int* cur1, int* sc1, float* sv1,
                         const int* __restrict__ r2, const int* __restrict__ q2, const float* __restrict__ v2,
                         int* cur2, int* sc2, float* sv2,
                         const int* __restrict__ r3, const int* __restrict__ q3, const float* __restrict__ v3,
                         int* cur3, int* sc3, float* sv3,
                         const int* __restrict__ r4, const int* __restrict__ q4, const float* __restrict__ v4,
                         int* cur4, int* sc4, float* sv4) {
  int g = blockIdx.x * blockDim.x + threadIdx.x;
  const int* r; const int* q; const float* v; int* cur; int* sc; float* sv; int e;
  if (g < E00) { r = r0; q = q0; v = v0; cur = cur0; sc = sc0; sv = sv0; e = g; }
  else if (g < E00 + E01) { r = r1; q = q1; v = v1; cur = cur1; sc = sc1; sv = sv1; e = g - E00; }
  else if (g < E00 + E01 + E10) { r = r2; q = q2; v = v2; cur = cur2; sc = sc2; sv = sv2; e = g - (E00 + E01); }
  else if (g < E00 + E01 + E10 + E11A) { r = r3; q = q3; v = v3; cur = cur3; sc = sc3; sv = sv3; e = g - (E00 + E01 + E10); }
  else if (g < NE_TOT) { r = r4; q = q4; v = v4; cur = cur4; sc = sc4; sv = sv4; e = g - (E00 + E01 + E10 + E11A); }
  else return;
  int row = r[e];
  int p = atomicAdd(&cur[row], 1);
  sc[p] = q[e];
  sv[p] = v[e];
}

// ---------- bf16 MFMA GEMM: C[M][N] = A[M][K] @ Bt[N][K]^T ----------
#define BM 128
#define BN 128
#define BK 64

__global__ __launch_bounds__(256) void gemm_bf16(const unsigned short* __restrict__ A,
                                                 const unsigned short* __restrict__ Bt,
                                                 unsigned short* __restrict__ C,
                                                 int M, int N, int K) {
  __shared__ unsigned short As[BM * BK];
  __shared__ unsigned short Bs[BN * BK];
  const int tid = threadIdx.x;
  const int lane = tid & 63;
  const int wid = tid >> 6;
  const int m0 = blockIdx.x * BM;
  const int n0 = blockIdx.y * BN;
  const int wm = (wid >> 1) * 64;
  const int wn = (wid & 1) * 64;

  f32x4 acc[4][4] = {};

  const int srow = wid * 32 + (lane >> 3);  // staging row within tile (+c*8)
  const int scol = (lane & 7) * 8;          // staging col (bf16 elems, 16B chunks)

  for (int k0 = 0; k0 < K; k0 += BK) {
    #pragma unroll
    for (int c = 0; c < 4; ++c) {
      int gr = m0 + srow + c * 8;
      if (gr > M - 1) gr = M - 1;
      gload16(A + (size_t)gr * K + k0 + scol, As + (wid * 32 + c * 8) * BK);
      int gn = n0 + srow + c * 8;  // N is a multiple of 128
      gload16(Bt + (size_t)gn * K + k0 + scol, Bs + (wid * 32 + c * 8) * BK);
    }
    __syncthreads();
    #pragma unroll
    for (int ks = 0; ks < 2; ++ks) {
      bf16x8 af[4], bfr[4];
      #pragma unroll
      for (int i = 0; i < 4; i++)
        af[i] = *(const bf16x8*)(As + (wm + i * 16 + (lane & 15)) * BK + ks * 32 + (lane >> 4) * 8);
      #pragma unroll
      for (int j = 0; j < 4; j++)
        bfr[j] = *(const bf16x8*)(Bs + (wn + j * 16 + (lane & 15)) * BK + ks * 32 + (lane >> 4) * 8);
      #pragma unroll
      for (int i = 0; i < 4; i++)
        #pragma unroll
        for (int j = 0; j < 4; j++)
          acc[i][j] = __builtin_amdgcn_mfma_f32_16x16x32_bf16(af[i], bfr[j], acc[i][j], 0, 0, 0);
    }
    __syncthreads();
  }

  #pragma unroll
  for (int i = 0; i < 4; i++) {
    int rbase = m0 + wm + i * 16 + (lane >> 4) * 4;
    #pragma unroll
    for (int j = 0; j < 4; j++) {
      int col = n0 + wn + j * 16 + (lane & 15);
      #pragma unroll
      for (int r = 0; r < 4; r++) {
        int row = rbase + r;
        if (row < M) C[(size_t)row * N + col] = f2bf(acc[i][j][r]);
      }
    }
  }
}

// ---------- CSR-gather SpMM (+relu, +bf16 store, +f32 final-out store) ----------
__global__ __launch_bounds__(256) void spmm_kernel(
    int nrows, int nseg,
    const int* __restrict__ rp0, const int* __restrict__ ci0, const float* __restrict__ cv0,
    const unsigned short* __restrict__ g0, int ld0, int off0,
    const int* __restrict__ rp1, const int* __restrict__ ci1, const float* __restrict__ cv1,
    const unsigned short* __restrict__ g1, int ld1, int off1,
    const int* __restrict__ rp2, const int* __restrict__ ci2, const float* __restrict__ cv2,
    const unsigned short* __restrict__ g2, int ld2, int off2,
    int do_relu,
    unsigned short* __restrict__ ebf,
    float* __restrict__ outp, int out_row0, int out_col0, int dup) {
  const int lane = threadIdx.x & 63;
  const int r = blockIdx.x * 4 + (threadIdx.x >> 6);
  if (r >= nrows) return;
  float acc[8] = {0.f, 0.f, 0.f, 0.f, 0.f, 0.f, 0.f, 0.f};
  for (int s = 0; s < nseg; ++s) {
    const int* rp; const int* ci; const float* cv; const unsigned short* g; int ld, off;
    if (s == 0) { rp = rp0; ci = ci0; cv = cv0; g = g0; ld = ld0; off = off0; }
    else if (s == 1) { rp = rp1; ci = ci1; cv = cv1; g = g1; ld = ld1; off = off1; }
    else { rp = rp2; ci = ci2; cv = cv2; g = g2; ld = ld2; off = off2; }
    const unsigned short* gb = g + off + lane * 8;
    int e = rp[r], e1 = rp[r + 1];
    for (; e < e1; ++e) {
      int c = ci[e];
      float v = cv[e];
      uint4 u = *(const uint4*)(gb + (size_t)c * ld);
      acc[0] += v * __uint_as_float(u.x << 16);
      acc[1] += v * __uint_as_float(u.x & 0xffff0000u);
      acc[2] += v * __uint_as_float(u.y << 16);
      acc[3] += v * __uint_as_float(u.y & 0xffff0000u);
      acc[4] += v * __uint_as_float(u.z << 16);
      acc[5] += v * __uint_as_float(u.z & 0xffff0000u);
      acc[6] += v * __uint_as_float(u.w << 16);
      acc[7] += v * __uint_as_float(u.w & 0xffff0000u);
    }
  }
  if (do_relu) {
    #pragma unroll
    for (int i = 0; i < 8; i++) acc[i] = fmaxf(acc[i], 0.f);
  }
  if (ebf) {
    uint4 o;
    o.x = (unsigned)f2bf(acc[0]) | ((unsigned)f2bf(acc[1]) << 16);
    o.y = (unsigned)f2bf(acc[2]) | ((unsigned)f2bf(acc[3]) << 16);
    o.z = (unsigned)f2bf(acc[4]) | ((unsigned)f2bf(acc[5]) << 16);
    o.w = (unsigned)f2bf(acc[6]) | ((unsigned)f2bf(acc[7]) << 16);
    *(uint4*)(ebf + (size_t)r * HDIM + lane * 8) = o;
  }
  if (outp) {
    float4 v0; v0.x = acc[0]; v0.y = acc[1]; v0.z = acc[2]; v0.w = acc[3];
    float4 v1; v1.x = acc[4]; v1.y = acc[5]; v1.z = acc[6]; v1.w = acc[7];
    size_t base = (size_t)(out_row0 + r) * 1536 + out_col0 + lane * 8;
    *(float4*)(outp + base) = v0;
    *(float4*)(outp + base + 4) = v1;
    if (dup) {
      *(float4*)(outp + base + 512) = v0;
      *(float4*)(outp + base + 516) = v1;
    }
  }
}

// ---------- host ----------
extern "C" void kernel_launch(void* const* d_in, const int* in_sizes, int n_in,
                              void* d_out, int out_size, void* d_ws, size_t ws_size,
                              hipStream_t stream) {
  const float* feat0 = (const float*)d_in[0];
  const float* feat1 = (const float*)d_in[1];
  const int* a00_row = (const int*)d_in[2];
  const int* a00_col = (const int*)d_in[3];
  const float* a00_val = (const float*)d_in[4];
  const int* a01_row = (const int*)d_in[5];
  const int* a01_col = (const int*)d_in[6];
  const float* a01_val = (const float*)d_in[7];
  const int* a10_row = (const int*)d_in[8];
  const int* a10_col = (const int*)d_in[9];
  const float* a10_val = (const float*)d_in[10];
  const int* a11a_row = (const int*)d_in[11];
  const int* a11a_col = (const int*)d_in[12];
  const float* a11a_val = (const float*)d_in[13];
  const int* a11b_row = (const int*)d_in[14];
  const int* a11b_col = (const int*)d_in[15];
  const float* a11b_val = (const float*)d_in[16];

  // Weight ordering: setup_inputs dict order interleaves W1/W2/W3 per relation.
  // Probe in_sizes[18] to be safe (262144 => dict/interleaved, 524288 => signature order).
  const float *W1[5], *W2[5], *W3[5];  // order: 00, 01, 10, 11a, 11b
  if (in_sizes[18] == 512 * 512) {
    static const int relmap[5] = {0, 1, 2, 3, 4};  // dict order: 00,01,10,11a,11b groups of 3
    for (int r = 0; r < 5; r++) {
      W1[relmap[r]] = (const float*)d_in[17 + 3 * r];
      W2[relmap[r]] = (const float*)d_in[18 + 3 * r];
      W3[relmap[r]] = (const float*)d_in[19 + 3 * r];
    }
  } else {
    for (int r = 0; r < 5; r++) {
      W1[r] = (const float*)d_in[17 + r];
      W2[r] = (const float*)d_in[22 + r];
      W3[r] = (const float*)d_in[27 + r];
    }
  }

  char* ws = (char*)d_ws;
  size_t off = 0;
  auto alloc = [&](size_t bytes) -> char* {
    char* p = ws + off;
    off += (bytes + 255) & ~(size_t)255;
    return p;
  };
  unsigned short* feat0b = (unsigned short*)alloc((size_t)N0 * FDIM * 2);  // later reused as e2_0
  unsigned short* feat1b = (unsigned short*)alloc((size_t)N1 * FDIM * 2);  // later reused as e2_1
  unsigned short* Wt1_0 = (unsigned short*)alloc((size_t)1024 * 1024 * 2);
  unsigned short* Wt1_1 = (unsigned short*)alloc((size_t)1536 * 1024 * 2);
  unsigned short* Wt2_0 = (unsigned short*)alloc((size_t)1024 * 512 * 2);
  unsigned short* Wt2_1 = (unsigned short*)alloc((size_t)1536 * 512 * 2);
  unsigned short* Wt3_0 = (unsigned short*)alloc((size_t)1024 * 512 * 2);
  unsigned short* Wt3_1 = (unsigned short*)alloc((size_t)1536 * 512 * 2);
  unsigned short* G0 = (unsigned short*)alloc((size_t)N0 * 1024 * 2);
  unsigned short* G1 = (unsigned short*)alloc((size_t)N1 * 1536 * 2);
  unsigned short* e0_0 = (unsigned short*)alloc((size_t)N0 * HDIM * 2);
  unsigned short* e0_1 = (unsigned short*)alloc((size_t)N1 * HDIM * 2);
  int* cur = (int*)alloc((size_t)(2 * N0 + 3 * N1) * 4);
  int* cur00 = cur;
  int* cur01 = cur + N0;
  int* cur10 = cur + 2 * N0;
  int* cur11a = cur + 2 * N0 + N1;
  int* cur11b = cur + 2 * N0 + 2 * N1;
  int* rp00 = (int*)alloc((N0 + 1) * 4);
  int* rp01 = (int*)alloc((N0 + 1) * 4);
  int* rp10 = (int*)alloc((N1 + 1) * 4);
  int* rp11a = (int*)alloc((N1 + 1) * 4);
  int* rp11b = (int*)alloc((N1 + 1) * 4);
  int* sc00 = (int*)alloc((size_t)E00 * 4);
  float* sv00 = (float*)alloc((size_t)E00 * 4);
  int* sc01 = (int*)alloc((size_t)E01 * 4);
  float* sv01 = (float*)alloc((size_t)E01 * 4);
  int* sc10 = (int*)alloc((size_t)E10 * 4);
  float* sv10 = (float*)alloc((size_t)E10 * 4);
  int* sc11a = (int*)alloc((size_t)E11A * 4);
  float* sv11a = (float*)alloc((size_t)E11A * 4);
  int* sc11b = (int*)alloc((size_t)E11B * 4);
  float* sv11b = (float*)alloc((size_t)E11B * 4);
  unsigned short* e2_0 = feat0b;  // alias: feats dead after layer-1 GEMMs
  unsigned short* e2_1 = feat1b;
  float* out = (float*)d_out;

  // --- conversions ---
  conv_bf16_kernel<<<(N0 * FDIM / 4 + 255) / 256, 256, 0, stream>>>(feat0, feat0b, N0 * FDIM / 4);
  conv_bf16_kernel<<<(N1 * FDIM / 4 + 255) / 256, 256, 0, stream>>>(feat1, feat1b, N1 * FDIM / 4);
  conv_weights_kernel<<<(2560 * 1024 + 255) / 256, 256, 0, stream>>>(W1[0], W1[2], W1[1], W1[3], W1[4], Wt1_0, Wt1_1, 1024);
  conv_weights_kernel<<<(2560 * 512 + 255) / 256, 256, 0, stream>>>(W2[0], W2[2], W2[1], W2[3], W2[4], Wt2_0, Wt2_1, 512);
  conv_weights_kernel<<<(2560 * 512 + 255) / 256, 256, 0, stream>>>(W3[0], W3[2], W3[1], W3[3], W3[4], Wt3_0, Wt3_1, 512);

  // --- CSR build ---
  int ncur = 2 * N0 + 3 * N1;
  zero_ints<<<(ncur + 255) / 256, 256, 0, stream>>>(cur, ncur);
  hist5<<<(NE_TOT + 255) / 256, 256, 0, stream>>>(a00_row, a01_row, a10_row, a11a_row, a11b_row,
                                                  cur00, cur01, cur10, cur11a, cur11b);
  scan5<<<1, 320, 0, stream>>>(cur00, rp00, cur01, rp01, cur10, rp10, cur11a, rp11a, cur11b, rp11b);
  scatter5<<<(NE_TOT + 255) / 256, 256, 0, stream>>>(
      a00_row, a00_col, a00_val, cur00, sc00, sv00,
      a01_row, a01_col, a01_val, cur01, sc01, sv01,
      a10_row, a10_col, a10_val, cur10, sc10, sv10,
      a11a_row, a11a_col, a11a_val, cur11a, sc11a, sv11a,
      a11b_row, a11b_col, a11b_val, cur11b, sc11b, sv11b);

  dim3 blk(256);
  dim3 g0a((N0 + BM - 1) / BM, 1024 / BN);
  dim3 g0b((N1 + BM - 1) / BM, 1536 / BN);

  // --- Layer 1 ---
  gemm_bf16<<<g0a, blk, 0, stream>>>(feat0b, Wt1_0, G0, N0, 1024, 1024);
  gemm_bf16<<<g0b, blk, 0, stream>>>(feat1b, Wt1_1, G1, N1, 1536, 1024);
  spmm_kernel<<<(N0 + 3) / 4, blk, 0, stream>>>(N0, 2,
      rp00, sc00, sv00, G0, 1024, 0,
      rp01, sc01, sv01, G1, 1536, 0,
      nullptr, nullptr, nullptr, nullptr, 0, 0,
      1, e0_0, out, 0, 0, 1);
  spmm_kernel<<<(N1 + 3) / 4, blk, 0, stream>>>(N1, 3,
      rp10, sc10, sv10, G0, 1024, 512,
      rp11a, sc11a, sv11a, G1, 1536, 512,
      rp11b, sc11b, sv11b, G1, 1536, 1024,
      1, e0_1, out, N0, 0, 1);

  // --- Layer 2 ---
  gemm_bf16<<<g0a, blk, 0, stream>>>(e0_0, Wt2_0, G0, N0, 1024, 512);
  gemm_bf16<<<g0b, blk, 0, stream>>>(e0_1, Wt2_1, G1, N1, 1536, 512);
  spmm_kernel<<<(N0 + 3) / 4, blk, 0, stream>>>(N0, 2,
      rp00, sc00, sv00, G0, 1024, 0,
      rp01, sc01, sv01, G1, 1536, 0,
      nullptr, nullptr, nullptr, nullptr, 0, 0,
      1, e2_0, nullptr, 0, 0, 0);
  spmm_kernel<<<(N1 + 3) / 4, blk, 0, stream>>>(N1, 3,
      rp10, sc10, sv10, G0, 1024, 512,
      rp11a, sc11a, sv11a, G1, 1536, 512,
      rp11b, sc11b, sv11b, G1, 1536, 1024,
      1, e2_1, nullptr, 0, 0, 0);

  // --- Layer 3 ---
  gemm_bf16<<<g0a, blk, 0, stream>>>(e2_0, Wt3_0, G0, N0, 1024, 512);
  gemm_bf16<<<g0b, blk, 0, stream>>>(e2_1, Wt3_1, G1, N1, 1536, 512);
  spmm_kernel<<<(N0 + 3) / 4, blk, 0, stream>>>(N0, 2,
      rp00, sc00, sv00, G0, 1024, 0,
      rp01, sc01, sv01, G1, 1536, 0,
      nullptr, nullptr, nullptr, nullptr, 0, 0,
      0, nullptr, out, 0, 1024, 0);
  spmm_kernel<<<(N1 + 3) / 4, blk, 0, stream>>>(N1, 3,
      rp10, sc10, sv10, G0, 1024, 512,
      rp11a, sc11a, sv11a, G1, 1536, 512,
      rp11b, sc11b, sv11b, G1, 1536, 1024,
      0, nullptr, out, N0, 1024, 0);
}

// Round 2
// 1347.365 us; speedup vs baseline: 1.2624x; 1.2624x over previous
//
#include <hip/hip_runtime.h>
#include <stdint.h>

#define N0 30000
#define N1 6000
#define FDIM 1024
#define HDIM 512
#define E00 600000
#define E01 300000
#define E10 300000
#define E11A 400000
#define E11B 400000
#define NE_TOT (E00 + E01 + E10 + E11A + E11B)

typedef __attribute__((ext_vector_type(4))) float f32x4;
typedef __attribute__((ext_vector_type(8))) __bf16 bf16x8;

// ---------- helpers ----------
__device__ __forceinline__ unsigned short f2bf(float f) {
  unsigned u = __float_as_uint(f);
  u += 0x7fffu + ((u >> 16) & 1u);   // round-to-nearest-even
  return (unsigned short)(u >> 16);
}

__device__ __forceinline__ void gload16(const void* g, void* l) {
  __builtin_amdgcn_global_load_lds((const __attribute__((address_space(1))) void*)g,
                                   (__attribute__((address_space(3))) void*)l, 16, 0, 0);
}

// ---------- conversion kernels ----------
__global__ void conv_bf16_kernel(const float* __restrict__ src, unsigned short* __restrict__ dst, int n4) {
  int gid = blockIdx.x * blockDim.x + threadIdx.x;
  if (gid >= n4) return;
  float4 v = ((const float4*)src)[gid];
  ushort4 o;
  o.x = f2bf(v.x); o.y = f2bf(v.y); o.z = f2bf(v.z); o.w = f2bf(v.w);
  ((ushort4*)dst)[gid] = o;
}

// Transpose-convert 5 weight matrices [K][512] f32 -> Wt blocks [N][K] bf16.
__global__ void conv_weights_kernel(const float* __restrict__ w00, const float* __restrict__ w10,
                                    const float* __restrict__ w01, const float* __restrict__ w11a,
                                    const float* __restrict__ w11b,
                                    unsigned short* __restrict__ dst0, unsigned short* __restrict__ dst1, int K) {
  int gid = blockIdx.x * blockDim.x + threadIdx.x;
  int total0 = 1024 * K;
  int total1 = 1536 * K;
  if (gid < total0) {
    int n = gid / K, k = gid - n * K;
    const float* w = (n < 512) ? w00 : w10;
    int nn = n & 511;
    dst0[gid] = f2bf(w[(size_t)k * 512 + nn]);
  } else if (gid < total0 + total1) {
    int g = gid - total0;
    int n = g / K, k = g - n * K;
    const float* w = (n < 512) ? w01 : ((n < 1024) ? w11a : w11b);
    int nn = n & 511;
    dst1[g] = f2bf(w[(size_t)k * 512 + nn]);
  }
}

// ---------- CSR build ----------
__global__ void zero_ints(int* p, int n) {
  int g = blockIdx.x * blockDim.x + threadIdx.x;
  if (g < n) p[g] = 0;
}

__global__ void hist5(const int* __restrict__ r0, const int* __restrict__ r1, const int* __restrict__ r2,
                      const int* __restrict__ r3, const int* __restrict__ r4,
                      int* c0, int* c1, int* c2, int* c3, int* c4) {
  int g = blockIdx.x * blockDim.x + threadIdx.x;
  const int* r; int* c; int e;
  if (g < E00) { r = r0; c = c0; e = g; }
  else if (g < E00 + E01) { r = r1; c = c1; e = g - E00; }
  else if (g < E00 + E01 + E10) { r = r2; c = c2; e = g - (E00 + E01); }
  else if (g < E00 + E01 + E10 + E11A) { r = r3; c = c3; e = g - (E00 + E01 + E10); }
  else if (g < NE_TOT) { r = r4; c = c4; e = g - (E00 + E01 + E10 + E11A); }
  else return;
  atomicAdd(&c[r[e]], 1);
}

// Parallel scan: one 1024-thread block per adjacency.
// Wave-level shfl scan + cross-wave LDS scan; ~n/1024 iterations with carry.
__global__ __launch_bounds__(1024) void scan5p(int* c0, int* rp0, int* c1, int* rp1,
                                               int* c2, int* rp2, int* c3, int* rp3,
                                               int* c4, int* rp4) {
  int b = blockIdx.x;
  int* cnt; int* rp; int n;
  if (b == 0) { cnt = c0; rp = rp0; n = N0; }
  else if (b == 1) { cnt = c1; rp = rp1; n = N0; }
  else if (b == 2) { cnt = c2; rp = rp2; n = N1; }
  else if (b == 3) { cnt = c3; rp = rp3; n = N1; }
  else { cnt = c4; rp = rp4; n = N1; }
  __shared__ int wsum[16];
  const int tid = threadIdx.x, lane = tid & 63, w = tid >> 6;
  int carry = 0;
  for (int base = 0; base < n; base += 1024) {
    int i = base + tid;
    int v = (i < n) ? cnt[i] : 0;
    int x = v;
    #pragma unroll
    for (int d = 1; d < 64; d <<= 1) {
      int y = __shfl_up(x, d, 64);
      if (lane >= d) x += y;
    }
    if (lane == 63) wsum[w] = x;
    __syncthreads();
    if (w == 0) {
      int t = (lane < 16) ? wsum[lane] : 0;
      #pragma unroll
      for (int d = 1; d < 16; d <<= 1) {
        int y = __shfl_up(t, d, 64);
        if (lane >= d) t += y;
      }
      if (lane < 16) wsum[lane] = t;
    }
    __syncthreads();
    int wpref = (w > 0) ? wsum[w - 1] : 0;
    int excl = carry + wpref + (x - v);
    if (i < n) { rp[i] = excl; cnt[i] = excl; }
    carry += wsum[15];
    __syncthreads();
  }
  if (tid == 0) rp[n] = carry;
}

__global__ void scatter5(const int* __restrict__ r0, const int* __restrict__ q0, const float* __restrict__ v0,
                         int* cur0, int* sc0, float* sv0,
                         const int* __restrict__ r1, const int* __restrict__ q1, const float* __restrict__ v1,
                         int* cur1, int* sc1, float* sv1,
                         const int* __restrict__ r2, const int* __restrict__ q2, const float* __restrict__ v2,
                         int* cur2, int* sc2, float* sv2,
                         const int* __restrict__ r3, const int* __restrict__ q3, const float* __restrict__ v3,
                         int* cur3, int* sc3, float* sv3,
                         const int* __restrict__ r4, const int* __restrict__ q4, const float* __restrict__ v4,
                         int* cur4, int* sc4, float* sv4) {
  int g = blockIdx.x * blockDim.x + threadIdx.x;
  const int* r; const int* q; const float* v; int* cur; int* sc; float* sv; int e;
  if (g < E00) { r = r0; q = q0; v = v0; cur = cur0; sc = sc0; sv = sv0; e = g; }
  else if (g < E00 + E01) { r = r1; q = q1; v = v1; cur = cur1; sc = sc1; sv = sv1; e = g - E00; }
  else if (g < E00 + E01 + E10) { r = r2; q = q2; v = v2; cur = cur2; sc = sc2; sv = sv2; e = g - (E00 + E01); }
  else if (g < E00 + E01 + E10 + E11A) { r = r3; q = q3; v = v3; cur = cur3; sc = sc3; sv = sv3; e = g - (E00 + E01 + E10); }
  else if (g < NE_TOT) { r = r4; q = q4; v = v4; cur = cur4; sc = sc4; sv = sv4; e = g - (E00 + E01 + E10 + E11A); }
  else return;
  int row = r[e];
  int p = atomicAdd(&cur[row], 1);
  sc[p] = q[e];
  sv[p] = v[e];
}

// ---------- bf16 MFMA GEMM: C[M][N] = A[M][K] @ Bt[N][K]^T ----------
#define BM 128
#define BN 128
#define BK 64

__global__ __launch_bounds__(256) void gemm_bf16(const unsigned short* __restrict__ A,
                                                 const unsigned short* __restrict__ Bt,
                                                 unsigned short* __restrict__ C,
                                                 int M, int N, int K, int nbx) {
  __shared__ unsigned short As[BM * BK];
  __shared__ unsigned short Bs[BN * BK];
  // T1: bijective XCD-aware swizzle (m204). Consecutive wg share the B panel;
  // chunking per-XCD keeps that panel resident in one XCD's L2.
  const int nwg = gridDim.x;
  const int orig = blockIdx.x;
  const int q = nwg >> 3, rr = nwg & 7;
  const int xcd = orig & 7, pos = orig >> 3;
  const int wg = (xcd < rr ? xcd * (q + 1) : rr * (q + 1) + (xcd - rr) * q) + pos;
  const int bx = wg % nbx;
  const int by = wg / nbx;

  const int tid = threadIdx.x;
  const int lane = tid & 63;
  const int wid = tid >> 6;
  const int m0 = bx * BM;
  const int n0 = by * BN;
  const int wm = (wid >> 1) * 64;
  const int wn = (wid & 1) * 64;

  f32x4 acc[4][4] = {};

  const int srow = wid * 32 + (lane >> 3);
  const int scol = (lane & 7) * 8;

  for (int k0 = 0; k0 < K; k0 += BK) {
    #pragma unroll
    for (int c = 0; c < 4; ++c) {
      int gr = m0 + srow + c * 8;
      if (gr > M - 1) gr = M - 1;
      gload16(A + (size_t)gr * K + k0 + scol, As + (wid * 32 + c * 8) * BK);
      int gn = n0 + srow + c * 8;
      gload16(Bt + (size_t)gn * K + k0 + scol, Bs + (wid * 32 + c * 8) * BK);
    }
    __syncthreads();
    #pragma unroll
    for (int ks = 0; ks < 2; ++ks) {
      bf16x8 af[4], bfr[4];
      #pragma unroll
      for (int i = 0; i < 4; i++)
        af[i] = *(const bf16x8*)(As + (wm + i * 16 + (lane & 15)) * BK + ks * 32 + (lane >> 4) * 8);
      #pragma unroll
      for (int j = 0; j < 4; j++)
        bfr[j] = *(const bf16x8*)(Bs + (wn + j * 16 + (lane & 15)) * BK + ks * 32 + (lane >> 4) * 8);
      #pragma unroll
      for (int i = 0; i < 4; i++)
        #pragma unroll
        for (int j = 0; j < 4; j++)
          acc[i][j] = __builtin_amdgcn_mfma_f32_16x16x32_bf16(af[i], bfr[j], acc[i][j], 0, 0, 0);
    }
    __syncthreads();
  }

  #pragma unroll
  for (int i = 0; i < 4; i++) {
    int rbase = m0 + wm + i * 16 + (lane >> 4) * 4;
    #pragma unroll
    for (int j = 0; j < 4; j++) {
      int col = n0 + wn + j * 16 + (lane & 15);
      #pragma unroll
      for (int r = 0; r < 4; r++) {
        int row = rbase + r;
        if (row < M) C[(size_t)row * N + col] = f2bf(acc[i][j][r]);
      }
    }
  }
}

// ---------- CSR-gather SpMM (+relu, +bf16 store, +f32 final-out store) ----------
__device__ __forceinline__ void acc8(float* acc, float v, uint4 u) {
  acc[0] += v * __uint_as_float(u.x << 16);
  acc[1] += v * __uint_as_float(u.x & 0xffff0000u);
  acc[2] += v * __uint_as_float(u.y << 16);
  acc[3] += v * __uint_as_float(u.y & 0xffff0000u);
  acc[4] += v * __uint_as_float(u.z << 16);
  acc[5] += v * __uint_as_float(u.z & 0xffff0000u);
  acc[6] += v * __uint_as_float(u.w << 16);
  acc[7] += v * __uint_as_float(u.w & 0xffff0000u);
}

__global__ __launch_bounds__(256) void spmm_kernel(
    int nrows, int nseg,
    const int* __restrict__ rp0, const int* __restrict__ ci0, const float* __restrict__ cv0,
    const unsigned short* __restrict__ g0, int ld0, int off0,
    const int* __restrict__ rp1, const int* __restrict__ ci1, const float* __restrict__ cv1,
    const unsigned short* __restrict__ g1, int ld1, int off1,
    const int* __restrict__ rp2, const int* __restrict__ ci2, const float* __restrict__ cv2,
    const unsigned short* __restrict__ g2, int ld2, int off2,
    int do_relu,
    unsigned short* __restrict__ ebf,
    float* __restrict__ outp, int out_row0, int out_col0, int dup) {
  const int lane = threadIdx.x & 63;
  const int r = blockIdx.x * 4 + (threadIdx.x >> 6);
  if (r >= nrows) return;
  float acc[8] = {0.f, 0.f, 0.f, 0.f, 0.f, 0.f, 0.f, 0.f};
  for (int s = 0; s < nseg; ++s) {
    const int* rp; const int* ci; const float* cv; const unsigned short* g; int ld, off;
    if (s == 0) { rp = rp0; ci = ci0; cv = cv0; g = g0; ld = ld0; off = off0; }
    else if (s == 1) { rp = rp1; ci = ci1; cv = cv1; g = g1; ld = ld1; off = off1; }
    else { rp = rp2; ci = ci2; cv = cv2; g = g2; ld = ld2; off = off2; }
    const unsigned short* gb = g + off + lane * 8;
    int e = rp[r], e1 = rp[r + 1];
    // unroll-4: 4 independent gathers in flight per iteration
    for (; e + 3 < e1; e += 4) {
      int ca = ci[e], cb = ci[e + 1], cc = ci[e + 2], cd = ci[e + 3];
      float va = cv[e], vb = cv[e + 1], vc = cv[e + 2], vd = cv[e + 3];
      uint4 ua = *(const uint4*)(gb + (size_t)ca * ld);
      uint4 ub = *(const uint4*)(gb + (size_t)cb * ld);
      uint4 uc = *(const uint4*)(gb + (size_t)cc * ld);
      uint4 ud = *(const uint4*)(gb + (size_t)cd * ld);
      acc8(acc, va, ua); acc8(acc, vb, ub); acc8(acc, vc, uc); acc8(acc, vd, ud);
    }
    for (; e < e1; ++e) {
      int c = ci[e];
      float v = cv[e];
      uint4 u = *(const uint4*)(gb + (size_t)c * ld);
      acc8(acc, v, u);
    }
  }
  if (do_relu) {
    #pragma unroll
    for (int i = 0; i < 8; i++) acc[i] = fmaxf(acc[i], 0.f);
  }
  if (ebf) {
    uint4 o;
    o.x = (unsigned)f2bf(acc[0]) | ((unsigned)f2bf(acc[1]) << 16);
    o.y = (unsigned)f2bf(acc[2]) | ((unsigned)f2bf(acc[3]) << 16);
    o.z = (unsigned)f2bf(acc[4]) | ((unsigned)f2bf(acc[5]) << 16);
    o.w = (unsigned)f2bf(acc[6]) | ((unsigned)f2bf(acc[7]) << 16);
    *(uint4*)(ebf + (size_t)r * HDIM + lane * 8) = o;
  }
  if (outp) {
    float4 v0; v0.x = acc[0]; v0.y = acc[1]; v0.z = acc[2]; v0.w = acc[3];
    float4 v1; v1.x = acc[4]; v1.y = acc[5]; v1.z = acc[6]; v1.w = acc[7];
    size_t base = (size_t)(out_row0 + r) * 1536 + out_col0 + lane * 8;
    *(float4*)(outp + base) = v0;
    *(float4*)(outp + base + 4) = v1;
    if (dup) {
      *(float4*)(outp + base + 512) = v0;
      *(float4*)(outp + base + 516) = v1;
    }
  }
}

// ---------- host ----------
extern "C" void kernel_launch(void* const* d_in, const int* in_sizes, int n_in,
                              void* d_out, int out_size, void* d_ws, size_t ws_size,
                              hipStream_t stream) {
  const float* feat0 = (const float*)d_in[0];
  const float* feat1 = (const float*)d_in[1];
  const int* a00_row = (const int*)d_in[2];
  const int* a00_col = (const int*)d_in[3];
  const float* a00_val = (const float*)d_in[4];
  const int* a01_row = (const int*)d_in[5];
  const int* a01_col = (const int*)d_in[6];
  const float* a01_val = (const float*)d_in[7];
  const int* a10_row = (const int*)d_in[8];
  const int* a10_col = (const int*)d_in[9];
  const float* a10_val = (const float*)d_in[10];
  const int* a11a_row = (const int*)d_in[11];
  const int* a11a_col = (const int*)d_in[12];
  const float* a11a_val = (const float*)d_in[13];
  const int* a11b_row = (const int*)d_in[14];
  const int* a11b_col = (const int*)d_in[15];
  const float* a11b_val = (const float*)d_in[16];

  const float *W1[5], *W2[5], *W3[5];  // order: 00, 01, 10, 11a, 11b
  if (in_sizes[18] == 512 * 512) {
    for (int r = 0; r < 5; r++) {
      W1[r] = (const float*)d_in[17 + 3 * r];
      W2[r] = (const float*)d_in[18 + 3 * r];
      W3[r] = (const float*)d_in[19 + 3 * r];
    }
  } else {
    for (int r = 0; r < 5; r++) {
      W1[r] = (const float*)d_in[17 + r];
      W2[r] = (const float*)d_in[22 + r];
      W3[r] = (const float*)d_in[27 + r];
    }
  }

  char* ws = (char*)d_ws;
  size_t off = 0;
  auto alloc = [&](size_t bytes) -> char* {
    char* p = ws + off;
    off += (bytes + 255) & ~(size_t)255;
    return p;
  };
  unsigned short* feat0b = (unsigned short*)alloc((size_t)N0 * FDIM * 2);  // reused as e2_0
  unsigned short* feat1b = (unsigned short*)alloc((size_t)N1 * FDIM * 2);  // reused as e2_1
  unsigned short* Wt1_0 = (unsigned short*)alloc((size_t)1024 * 1024 * 2);
  unsigned short* Wt1_1 = (unsigned short*)alloc((size_t)1536 * 1024 * 2);
  unsigned short* Wt2_0 = (unsigned short*)alloc((size_t)1024 * 512 * 2);
  unsigned short* Wt2_1 = (unsigned short*)alloc((size_t)1536 * 512 * 2);
  unsigned short* Wt3_0 = (unsigned short*)alloc((size_t)1024 * 512 * 2);
  unsigned short* Wt3_1 = (unsigned short*)alloc((size_t)1536 * 512 * 2);
  unsigned short* G0 = (unsigned short*)alloc((size_t)N0 * 1024 * 2);
  unsigned short* G1 = (unsigned short*)alloc((size_t)N1 * 1536 * 2);
  unsigned short* e0_0 = (unsigned short*)alloc((size_t)N0 * HDIM * 2);
  unsigned short* e0_1 = (unsigned short*)alloc((size_t)N1 * HDIM * 2);
  int* cur = (int*)alloc((size_t)(2 * N0 + 3 * N1) * 4);
  int* cur00 = cur;
  int* cur01 = cur + N0;
  int* cur10 = cur + 2 * N0;
  int* cur11a = cur + 2 * N0 + N1;
  int* cur11b = cur + 2 * N0 + 2 * N1;
  int* rp00 = (int*)alloc((N0 + 1) * 4);
  int* rp01 = (int*)alloc((N0 + 1) * 4);
  int* rp10 = (int*)alloc((N1 + 1) * 4);
  int* rp11a = (int*)alloc((N1 + 1) * 4);
  int* rp11b = (int*)alloc((N1 + 1) * 4);
  int* sc00 = (int*)alloc((size_t)E00 * 4);
  float* sv00 = (float*)alloc((size_t)E00 * 4);
  int* sc01 = (int*)alloc((size_t)E01 * 4);
  float* sv01 = (float*)alloc((size_t)E01 * 4);
  int* sc10 = (int*)alloc((size_t)E10 * 4);
  float* sv10 = (float*)alloc((size_t)E10 * 4);
  int* sc11a = (int*)alloc((size_t)E11A * 4);
  float* sv11a = (float*)alloc((size_t)E11A * 4);
  int* sc11b = (int*)alloc((size_t)E11B * 4);
  float* sv11b = (float*)alloc((size_t)E11B * 4);
  unsigned short* e2_0 = feat0b;
  unsigned short* e2_1 = feat1b;
  float* out = (float*)d_out;

  // --- conversions ---
  conv_bf16_kernel<<<(N0 * FDIM / 4 + 255) / 256, 256, 0, stream>>>(feat0, feat0b, N0 * FDIM / 4);
  conv_bf16_kernel<<<(N1 * FDIM / 4 + 255) / 256, 256, 0, stream>>>(feat1, feat1b, N1 * FDIM / 4);
  conv_weights_kernel<<<(2560 * 1024 + 255) / 256, 256, 0, stream>>>(W1[0], W1[2], W1[1], W1[3], W1[4], Wt1_0, Wt1_1, 1024);
  conv_weights_kernel<<<(2560 * 512 + 255) / 256, 256, 0, stream>>>(W2[0], W2[2], W2[1], W2[3], W2[4], Wt2_0, Wt2_1, 512);
  conv_weights_kernel<<<(2560 * 512 + 255) / 256, 256, 0, stream>>>(W3[0], W3[2], W3[1], W3[3], W3[4], Wt3_0, Wt3_1, 512);

  // --- CSR build ---
  int ncur = 2 * N0 + 3 * N1;
  zero_ints<<<(ncur + 255) / 256, 256, 0, stream>>>(cur, ncur);
  hist5<<<(NE_TOT + 255) / 256, 256, 0, stream>>>(a00_row, a01_row, a10_row, a11a_row, a11b_row,
                                                  cur00, cur01, cur10, cur11a, cur11b);
  scan5p<<<5, 1024, 0, stream>>>(cur00, rp00, cur01, rp01, cur10, rp10, cur11a, rp11a, cur11b, rp11b);
  scatter5<<<(NE_TOT + 255) / 256, 256, 0, stream>>>(
      a00_row, a00_col, a00_val, cur00, sc00, sv00,
      a01_row, a01_col, a01_val, cur01, sc01, sv01,
      a10_row, a10_col, a10_val, cur10, sc10, sv10,
      a11a_row, a11a_col, a11a_val, cur11a, sc11a, sv11a,
      a11b_row, a11b_col, a11b_val, cur11b, sc11b, sv11b);

  dim3 blk(256);
  int nbx0 = (N0 + BM - 1) / BM;
  int nbx1 = (N1 + BM - 1) / BM;
  dim3 g0a(nbx0 * (1024 / BN));
  dim3 g0b(nbx1 * (1536 / BN));

  // --- Layer 1 ---
  gemm_bf16<<<g0a, blk, 0, stream>>>(feat0b, Wt1_0, G0, N0, 1024, 1024, nbx0);
  gemm_bf16<<<g0b, blk, 0, stream>>>(feat1b, Wt1_1, G1, N1, 1536, 1024, nbx1);
  spmm_kernel<<<(N0 + 3) / 4, blk, 0, stream>>>(N0, 2,
      rp00, sc00, sv00, G0, 1024, 0,
      rp01, sc01, sv01, G1, 1536, 0,
      nullptr, nullptr, nullptr, nullptr, 0, 0,
      1, e0_0, out, 0, 0, 1);
  spmm_kernel<<<(N1 + 3) / 4, blk, 0, stream>>>(N1, 3,
      rp10, sc10, sv10, G0, 1024, 512,
      rp11a, sc11a, sv11a, G1, 1536, 512,
      rp11b, sc11b, sv11b, G1, 1536, 1024,
      1, e0_1, out, N0, 0, 1);

  // --- Layer 2 ---
  gemm_bf16<<<g0a, blk, 0, stream>>>(e0_0, Wt2_0, G0, N0, 1024, 512, nbx0);
  gemm_bf16<<<g0b, blk, 0, stream>>>(e0_1, Wt2_1, G1, N1, 1536, 512, nbx1);
  spmm_kernel<<<(N0 + 3) / 4, blk, 0, stream>>>(N0, 2,
      rp00, sc00, sv00, G0, 1024, 0,
      rp01, sc01, sv01, G1, 1536, 0,
      nullptr, nullptr, nullptr, nullptr, 0, 0,
      1, e2_0, nullptr, 0, 0, 0);
  spmm_kernel<<<(N1 + 3) / 4, blk, 0, stream>>>(N1, 3,
      rp10, sc10, sv10, G0, 1024, 512,
      rp11a, sc11a, sv11a, G1, 1536, 512,
      rp11b, sc11b, sv11b, G1, 1536, 1024,
      1, e2_1, nullptr, 0, 0, 0);

  // --- Layer 3 ---
  gemm_bf16<<<g0a, blk, 0, stream>>>(e2_0, Wt3_0, G0, N0, 1024, 512, nbx0);
  gemm_bf16<<<g0b, blk, 0, stream>>>(e2_1, Wt3_1, G1, N1, 1536, 512, nbx1);
  spmm_kernel<<<(N0 + 3) / 4, blk, 0, stream>>>(N0, 2,
      rp00, sc00, sv00, G0, 1024, 0,
      rp01, sc01, sv01, G1, 1536, 0,
      nullptr, nullptr, nullptr, nullptr, 0, 0,
      0, nullptr, out, 0, 1024, 0);
  spmm_kernel<<<(N1 + 3) / 4, blk, 0, stream>>>(N1, 3,
      rp10, sc10, sv10, G0, 1024, 512,
      rp11a, sc11a, sv11a, G1, 1536, 512,
      rp11b, sc11b, sv11b, G1, 1536, 1024,
      0, nullptr, out, N0, 1024, 0);
}